// Round 1
// baseline (714.324 us; speedup 1.0000x reference)
//
#include <hip/hip_runtime.h>
#include <hip/hip_bf16.h>

#define N_POINTS   262144
#define D_EMBED    512
#define N_CLUSTERS 64
#define LAMBD      0.1f

#define BLK_PTS 64          // points per block
#define KC      128         // K-chunk (d's staged per pass)
#define NCHUNK  (D_EMBED / KC)   // 4
#define ROWP    (KC + 8)    // padded LDS row in bf16 elems (16B-aligned rows, +4 bank shift/row)

typedef __attribute__((ext_vector_type(8))) short  short8;   // 8 bf16 (4 VGPRs)
typedef __attribute__((ext_vector_type(4))) float  f32x4;    // MFMA accumulator

__device__ __forceinline__ unsigned short f2bf(float f) {
    union { float f; unsigned u; } v; v.f = f;
    unsigned u = v.u;
    // round-to-nearest-even fp32 -> bf16
    return (unsigned short)((u + 0x7FFFu + ((u >> 16) & 1u)) >> 16);
}

// ---------------------------------------------------------------------------
// Prep: c2[k], centroid A-fragments (bf16, MFMA A-operand order), zero d_out.
// A-frag layout: afrag[((s*4 + t)*64 + lane)*8 + j] =
//   bf16( cent[16*t + (lane&15)][32*s + (lane>>4)*8 + j] )
// grid 64 blocks (one per cluster), 64 threads.
// ---------------------------------------------------------------------------
__global__ void prep_kernel(const float* __restrict__ cent,
                            float* __restrict__ c2_ws,
                            unsigned short* __restrict__ afrag_ws,
                            float* __restrict__ out) {
    const int k    = blockIdx.x;     // cluster
    const int lane = threadIdx.x;    // 0..63, handles d = lane*8 .. lane*8+7
    const float* row = cent + (size_t)k * D_EMBED;

    float4 v0 = ((const float4*)row)[lane * 2 + 0];
    float4 v1 = ((const float4*)row)[lane * 2 + 1];

    float s = v0.x*v0.x + v0.y*v0.y + v0.z*v0.z + v0.w*v0.w
            + v1.x*v1.x + v1.y*v1.y + v1.z*v1.z + v1.w*v1.w;
    #pragma unroll
    for (int m = 1; m < 64; m <<= 1) s += __shfl_xor(s, m);
    if (lane == 0) c2_ws[k] = s;

    // d = lane*8+j  ->  sstep = lane>>2, q = lane&3, j = 0..7
    const int sstep = lane >> 2;
    const int q     = lane & 3;
    const int t     = k >> 4;
    const size_t idx8 = ((size_t)(sstep * 4 + t) * 64 + q * 16 + (k & 15)) * 8;

    ushort4 h0, h1;
    h0.x = f2bf(v0.x); h0.y = f2bf(v0.y); h0.z = f2bf(v0.z); h0.w = f2bf(v0.w);
    h1.x = f2bf(v1.x); h1.y = f2bf(v1.y); h1.z = f2bf(v1.z); h1.w = f2bf(v1.w);
    *(ushort4*)&afrag_ws[idx8 + 0] = h0;
    *(ushort4*)&afrag_ws[idx8 + 4] = h1;

    if (k == 0 && lane == 0) *out = 0.0f;   // d_out is poisoned 0xAA each call
}

// ---------------------------------------------------------------------------
// Main: per block 64 points; per wave 16 points x 64 clusters via
// 4 M-tiles of mfma_f32_16x16x32_bf16, K chunked by 128 through LDS.
// ---------------------------------------------------------------------------
__global__ __launch_bounds__(256, 4)
void main_kernel(const float* __restrict__ x,
                 const int* __restrict__ alpha_p,
                 const float* __restrict__ c2_ws,
                 const unsigned short* __restrict__ afrag_ws,
                 float* __restrict__ out) {
    __shared__ unsigned short xlds[BLK_PTS * ROWP];   // 64*136*2 = 17408 B
    __shared__ float c2s[N_CLUSTERS];
    __shared__ float x2s[BLK_PTS];
    __shared__ float blocksum_s[4];

    const int tid  = threadIdx.x;
    const int lane = tid & 63;
    const int w    = tid >> 6;            // wave 0..3
    const size_t base = (size_t)blockIdx.x * BLK_PTS;

    if (tid < 64) { c2s[tid] = c2_ws[tid]; x2s[tid] = 0.0f; }
    __syncthreads();

    const float alpha = (float)alpha_p[0];
    const int p = lane & 15;              // point-in-wave / C/D col
    const int q = lane >> 4;              // quad

    f32x4 acc[4] = {f32x4{0,0,0,0}, f32x4{0,0,0,0}, f32x4{0,0,0,0}, f32x4{0,0,0,0}};

    for (int c = 0; c < NCHUNK; ++c) {
        // ---- stage chunk: 64 rows x 128 d  (2048 float4 / 256 thr = 8 iters)
        #pragma unroll
        for (int it = 0; it < 8; ++it) {
            const int f    = it * 256 + tid;
            const int row  = f >> 5;          // 32 float4 per row-chunk
            const int col4 = f & 31;
            float4 v = ((const float4*)(x + (base + row) * D_EMBED + c * KC))[col4];

            float sq = v.x*v.x + v.y*v.y + v.z*v.z + v.w*v.w;
            sq += __shfl_xor(sq, 1);
            sq += __shfl_xor(sq, 2);
            sq += __shfl_xor(sq, 4);
            sq += __shfl_xor(sq, 8);
            sq += __shfl_xor(sq, 16);
            if ((lane & 31) == 0) x2s[row] += sq;   // unique (row <- wave,it) pairs

            ushort4 h;
            h.x = f2bf(v.x); h.y = f2bf(v.y); h.z = f2bf(v.z); h.w = f2bf(v.w);
            *(ushort4*)&xlds[row * ROWP + col4 * 4] = h;
        }
        __syncthreads();

        // ---- MFMA: 4 K-steps of 32 over this chunk
        #pragma unroll
        for (int sl = 0; sl < 4; ++sl) {
            const int s = c * 4 + sl;
            short8 b = *(const short8*)&xlds[(16 * w + p) * ROWP + sl * 32 + q * 8];
            #pragma unroll
            for (int t = 0; t < 4; ++t) {
                short8 a = *(const short8*)&afrag_ws[((size_t)(s * 4 + t) * 64 + lane) * 8];
                acc[t] = __builtin_amdgcn_mfma_f32_16x16x32_bf16(a, b, acc[t], 0, 0, 0);
            }
        }
        __syncthreads();   // before next chunk overwrites xlds
    }

    // ---- epilogue: dist -> soft-min per point
    // C/D layout: col = lane&15 = point p, row(in 16-tile) = q*4 + reg
    const float x2 = x2s[16 * w + p];
    float dist[16];
    float minv = 1e30f;
    #pragma unroll
    for (int t = 0; t < 4; ++t) {
        #pragma unroll
        for (int r = 0; r < 4; ++r) {
            const int cl = 16 * t + q * 4 + r;
            const float d = x2 + c2s[cl] - 2.0f * acc[t][r];
            dist[t * 4 + r] = d;
            minv = fminf(minv, d);
        }
    }
    // 4 lanes (q=0..3) share one point: reduce across xor-16, xor-32
    minv = fminf(minv, __shfl_xor(minv, 16));
    minv = fminf(minv, __shfl_xor(minv, 32));

    float esum = 0.0f, wsum = 0.0f;
    #pragma unroll
    for (int i = 0; i < 16; ++i) {
        const float e = __expf(-alpha * (dist[i] - minv));
        esum += e;
        wsum += dist[i] * e;
    }
    esum += __shfl_xor(esum, 16);
    esum += __shfl_xor(esum, 32);
    wsum += __shfl_xor(wsum, 16);
    wsum += __shfl_xor(wsum, 32);

    float pv = wsum / esum;               // per-point value, 4 copies per point
    #pragma unroll
    for (int m = 1; m < 64; m <<= 1) pv += __shfl_xor(pv, m);  // = 4 * sum_pts

    if (lane == 0) blocksum_s[w] = pv;
    __syncthreads();
    if (tid == 0) {
        const float T = blocksum_s[0] + blocksum_s[1] + blocksum_s[2] + blocksum_s[3];
        atomicAdd(out, T * (LAMBD / (4.0f * (float)N_POINTS)));
    }
}

extern "C" void kernel_launch(void* const* d_in, const int* in_sizes, int n_in,
                              void* d_out, int out_size, void* d_ws, size_t ws_size,
                              hipStream_t stream) {
    const float* x      = (const float*)d_in[0];
    const float* cent   = (const float*)d_in[1];
    const int*   alphap = (const int*)d_in[2];
    float* out = (float*)d_out;

    float*          c2_ws = (float*)d_ws;                             // 256 B
    unsigned short* afrag = (unsigned short*)((char*)d_ws + 256);     // 64 KiB

    hipLaunchKernelGGL(prep_kernel, dim3(N_CLUSTERS), dim3(64), 0, stream,
                       cent, c2_ws, afrag, out);
    hipLaunchKernelGGL(main_kernel, dim3(N_POINTS / BLK_PTS), dim3(256), 0, stream,
                       x, alphap, c2_ws, afrag, out);
}

// Round 2
// 691.815 us; speedup vs baseline: 1.0325x; 1.0325x over previous
//
#include <hip/hip_runtime.h>
#include <hip/hip_bf16.h>

#define N_POINTS   262144
#define D_EMBED    512
#define N_CLUSTERS 64
#define LAMBD      0.1f

#define PTS_PER_WAVE  32
#define PTS_PER_BLK   128   // 4 waves

typedef __attribute__((ext_vector_type(8)))  short short8;   // 8 bf16 (4 VGPRs)
typedef __attribute__((ext_vector_type(16))) float f32x16;   // 32x32 MFMA C/D

__device__ __forceinline__ unsigned short f2bf(float f) {
    union { float f; unsigned u; } v; v.f = f;
    unsigned u = v.u;
    return (unsigned short)((u + 0x7FFFu + ((u >> 16) & 1u)) >> 16);  // RNE
}

// ---------------------------------------------------------------------------
// Prep: c2[k]; centroid A-fragments for v_mfma_f32_32x32x16_bf16.
// A layout (m = lane&31, k = 8*(lane>>5)+j):
//   afrag[((s*2 + t)*64 + m + 32*h)*8 + j] = bf16(cent[32t + m][16s + 8h + j])
// One block per cluster k; lane covers d = 8*lane .. 8*lane+7
//   -> s = lane>>1, h = lane&1, j = 0..7.
// ---------------------------------------------------------------------------
__global__ void prep_kernel(const float* __restrict__ cent,
                            float* __restrict__ c2_ws,
                            unsigned short* __restrict__ afrag,
                            float* __restrict__ out) {
    const int k    = blockIdx.x;
    const int lane = threadIdx.x;
    const float* row = cent + (size_t)k * D_EMBED;

    float4 v0 = ((const float4*)row)[lane * 2 + 0];
    float4 v1 = ((const float4*)row)[lane * 2 + 1];

    float s = v0.x*v0.x + v0.y*v0.y + v0.z*v0.z + v0.w*v0.w
            + v1.x*v1.x + v1.y*v1.y + v1.z*v1.z + v1.w*v1.w;
    #pragma unroll
    for (int m = 1; m < 64; m <<= 1) s += __shfl_xor(s, m);
    if (lane == 0) c2_ws[k] = s;

    const int st = lane >> 1;      // K-step (of 16)
    const int h  = lane & 1;       // k-half within step
    const int t  = k >> 5;         // cluster tile
    const int m  = k & 31;         // cluster within tile
    const size_t idx8 = ((size_t)(st * 2 + t) * 64 + m + 32 * h) * 8;

    ushort4 h0, h1;
    h0.x = f2bf(v0.x); h0.y = f2bf(v0.y); h0.z = f2bf(v0.z); h0.w = f2bf(v0.w);
    h1.x = f2bf(v1.x); h1.y = f2bf(v1.y); h1.z = f2bf(v1.z); h1.w = f2bf(v1.w);
    *(ushort4*)&afrag[idx8 + 0] = h0;
    *(ushort4*)&afrag[idx8 + 4] = h1;

    if (k == 0 && lane == 0) *out = 0.0f;   // d_out poisoned 0xAA every call
}

// ---------------------------------------------------------------------------
// Main: no LDS staging, no K-loop barriers. Each wave: 32 points x 64
// clusters via 2 tiles of mfma_f32_32x32x16_bf16. B-frag (x) loaded
// directly from global: lane (n=lane&31, h=lane>>5) reads
// x[point n][16s + 8h .. +7] — wave reads 64 contiguous B per row per step.
// ---------------------------------------------------------------------------
__global__ __launch_bounds__(256, 4)
void main_kernel(const float* __restrict__ x,
                 const int* __restrict__ alpha_p,
                 const float* __restrict__ c2_ws,
                 const unsigned short* __restrict__ afrag,
                 float* __restrict__ out) {
    __shared__ float c2s[N_CLUSTERS];
    __shared__ float bsum[4];

    const int tid  = threadIdx.x;
    const int lane = tid & 63;
    const int w    = tid >> 6;

    if (tid < 64) c2s[tid] = c2_ws[tid];
    __syncthreads();

    const float alpha = (float)alpha_p[0];
    const int n = lane & 31;          // point within wave / C/D col
    const int h = lane >> 5;          // k-half
    const size_t pt = (size_t)blockIdx.x * PTS_PER_BLK + w * PTS_PER_WAVE + n;
    const float* xp = x + pt * D_EMBED + 8 * h;

    f32x16 acc0, acc1;
    #pragma unroll
    for (int r = 0; r < 16; ++r) { acc0[r] = 0.0f; acc1[r] = 0.0f; }

    float x2 = 0.0f;
    #pragma unroll 4
    for (int s = 0; s < 32; ++s) {
        float4 u0 = *(const float4*)(xp + 16 * s);
        float4 u1 = *(const float4*)(xp + 16 * s + 4);

        x2 += u0.x*u0.x + u0.y*u0.y + u0.z*u0.z + u0.w*u0.w
            + u1.x*u1.x + u1.y*u1.y + u1.z*u1.z + u1.w*u1.w;

        short8 b;
        b[0] = (short)f2bf(u0.x); b[1] = (short)f2bf(u0.y);
        b[2] = (short)f2bf(u0.z); b[3] = (short)f2bf(u0.w);
        b[4] = (short)f2bf(u1.x); b[5] = (short)f2bf(u1.y);
        b[6] = (short)f2bf(u1.z); b[7] = (short)f2bf(u1.w);

        short8 a0 = *(const short8*)&afrag[((size_t)(s * 2 + 0) * 64 + lane) * 8];
        short8 a1 = *(const short8*)&afrag[((size_t)(s * 2 + 1) * 64 + lane) * 8];

        acc0 = __builtin_amdgcn_mfma_f32_32x32x16_bf16(a0, b, acc0, 0, 0, 0);
        acc1 = __builtin_amdgcn_mfma_f32_32x32x16_bf16(a1, b, acc1, 0, 0, 0);
    }
    x2 += __shfl_xor(x2, 32);   // combine the two k-halves of point n

    // dist in place of acc; C/D: col = lane&31 = point, row = (r&3)+8*(r>>2)+4*h
    float minv = 1e30f;
    #pragma unroll
    for (int r = 0; r < 16; ++r) {
        const int rr = (r & 3) + 8 * (r >> 2) + 4 * h;
        const float d0 = x2 + c2s[rr]      - 2.0f * acc0[r];
        const float d1 = x2 + c2s[rr + 32] - 2.0f * acc1[r];
        acc0[r] = d0; acc1[r] = d1;
        minv = fminf(minv, fminf(d0, d1));
    }
    minv = fminf(minv, __shfl_xor(minv, 32));

    float esum = 0.0f, wsum = 0.0f;
    #pragma unroll
    for (int r = 0; r < 16; ++r) {
        const float e0 = __expf(-alpha * (acc0[r] - minv));
        const float e1 = __expf(-alpha * (acc1[r] - minv));
        esum += e0 + e1;
        wsum += acc0[r] * e0 + acc1[r] * e1;
    }
    esum += __shfl_xor(esum, 32);
    wsum += __shfl_xor(wsum, 32);

    float pv = wsum / esum;                 // per-point value, 2 copies/point
    #pragma unroll
    for (int m = 1; m < 64; m <<= 1) pv += __shfl_xor(pv, m);   // 2 * sum(32 pts)

    if (lane == 0) bsum[w] = pv;
    __syncthreads();
    if (tid == 0) {
        const float T = bsum[0] + bsum[1] + bsum[2] + bsum[3];
        atomicAdd(out, T * (LAMBD / (2.0f * (float)N_POINTS)));
    }
}

extern "C" void kernel_launch(void* const* d_in, const int* in_sizes, int n_in,
                              void* d_out, int out_size, void* d_ws, size_t ws_size,
                              hipStream_t stream) {
    const float* x      = (const float*)d_in[0];
    const float* cent   = (const float*)d_in[1];
    const int*   alphap = (const int*)d_in[2];
    float* out = (float*)d_out;

    float*          c2_ws = (float*)d_ws;                          // 256 B
    unsigned short* afrag = (unsigned short*)((char*)d_ws + 256);  // 64 KiB

    hipLaunchKernelGGL(prep_kernel, dim3(N_CLUSTERS), dim3(64), 0, stream,
                       cent, c2_ws, afrag, out);
    hipLaunchKernelGGL(main_kernel, dim3(N_POINTS / PTS_PER_BLK), dim3(256), 0, stream,
                       x, alphap, c2_ws, afrag, out);
}

// Round 3
// 679.250 us; speedup vs baseline: 1.0516x; 1.0185x over previous
//
#include <hip/hip_runtime.h>
#include <hip/hip_bf16.h>

#define N_POINTS   262144
#define D_EMBED    512
#define N_CLUSTERS 64
#define LAMBD      0.1f

#define PTS_PER_WAVE  32
#define PTS_PER_BLK   128   // 4 waves

typedef __attribute__((ext_vector_type(8)))  short short8;   // 8 bf16 (4 VGPRs)
typedef __attribute__((ext_vector_type(16))) float f32x16;   // 32x32 MFMA C/D

__device__ __forceinline__ unsigned short f2bf(float f) {
    union { float f; unsigned u; } v; v.f = f;
    unsigned u = v.u;
    return (unsigned short)((u + 0x7FFFu + ((u >> 16) & 1u)) >> 16);  // RNE
}

// ---------------------------------------------------------------------------
// Prep: c2[k]; centroid A-fragments for v_mfma_f32_32x32x16_bf16.
// A layout (m = lane&31, k = 8*(lane>>5)+j):
//   afrag[((s*2 + t)*64 + m + 32*h)*8 + j] = bf16(cent[32t + m][16s + 8h + j])
// One block per cluster k; lane covers d = 8*lane .. 8*lane+7
//   -> s = lane>>1, h = lane&1, j = 0..7.
// ---------------------------------------------------------------------------
__global__ void prep_kernel(const float* __restrict__ cent,
                            float* __restrict__ c2_ws,
                            unsigned short* __restrict__ afrag,
                            float* __restrict__ out) {
    const int k    = blockIdx.x;
    const int lane = threadIdx.x;
    const float* row = cent + (size_t)k * D_EMBED;

    float4 v0 = ((const float4*)row)[lane * 2 + 0];
    float4 v1 = ((const float4*)row)[lane * 2 + 1];

    float s = v0.x*v0.x + v0.y*v0.y + v0.z*v0.z + v0.w*v0.w
            + v1.x*v1.x + v1.y*v1.y + v1.z*v1.z + v1.w*v1.w;
    #pragma unroll
    for (int m = 1; m < 64; m <<= 1) s += __shfl_xor(s, m);
    if (lane == 0) c2_ws[k] = s;

    const int st = lane >> 1;      // K-step (of 16)
    const int h  = lane & 1;       // k-half within step
    const int t  = k >> 5;         // cluster tile
    const int m  = k & 31;         // cluster within tile
    const size_t idx8 = ((size_t)(st * 2 + t) * 64 + m + 32 * h) * 8;

    ushort4 h0, h1;
    h0.x = f2bf(v0.x); h0.y = f2bf(v0.y); h0.z = f2bf(v0.z); h0.w = f2bf(v0.w);
    h1.x = f2bf(v1.x); h1.y = f2bf(v1.y); h1.z = f2bf(v1.z); h1.w = f2bf(v1.w);
    *(ushort4*)&afrag[idx8 + 0] = h0;
    *(ushort4*)&afrag[idx8 + 4] = h1;

    if (k == 0 && lane == 0) *out = 0.0f;   // d_out poisoned 0xAA every call
}

// ---------------------------------------------------------------------------
// Main: A-fragments staged in LDS once (K-loop VMEM = pure HBM x-stream).
// Each wave: 32 points x 64 clusters, 2 tiles of mfma_f32_32x32x16_bf16.
// x pipeline: double-buffered 8-step groups (16 dwordx4 in flight / wave).
// ---------------------------------------------------------------------------
__global__ __launch_bounds__(256, 2)
void main_kernel(const float* __restrict__ x,
                 const int* __restrict__ alpha_p,
                 const float* __restrict__ c2_ws,
                 const unsigned short* __restrict__ afrag,
                 float* __restrict__ out) {
    __shared__ unsigned short alds[64 * 64 * 8];   // 64 KiB: ((s*2+t)*64+lane)*8
    __shared__ float c2s[N_CLUSTERS];
    __shared__ float bsum[4];

    const int tid  = threadIdx.x;
    const int lane = tid & 63;
    const int w    = tid >> 6;

    // ---- stage all A-fragments to LDS (64 KB, coalesced, one barrier)
    #pragma unroll
    for (int it = 0; it < 16; ++it) {
        const int e8 = it * 256 + tid;              // 16B chunk index
        *(short8*)&alds[(size_t)e8 * 8] = *(const short8*)&afrag[(size_t)e8 * 8];
    }
    if (tid < 64) c2s[tid] = c2_ws[tid];
    __syncthreads();

    const float alpha = (float)alpha_p[0];
    const int n = lane & 31;          // point within wave / C/D col
    const int h = lane >> 5;          // k-half
    const size_t pt = (size_t)blockIdx.x * PTS_PER_BLK + w * PTS_PER_WAVE + n;
    const float* xp = x + pt * D_EMBED + 8 * h;

    f32x16 acc0, acc1;
    #pragma unroll
    for (int r = 0; r < 16; ++r) { acc0[r] = 0.0f; acc1[r] = 0.0f; }

    // ---- K-loop: 4 groups x 8 steps (K=16/step), double-buffered x regs
    float4 buf[2][16];
    #pragma unroll
    for (int i = 0; i < 8; ++i) {
        buf[0][2*i+0] = *(const float4*)(xp + 16 * i);
        buf[0][2*i+1] = *(const float4*)(xp + 16 * i + 4);
    }

    float x2 = 0.0f;
    #pragma unroll
    for (int g = 0; g < 4; ++g) {
        const int cb = g & 1, nb = cb ^ 1;
        if (g < 3) {
            #pragma unroll
            for (int i = 0; i < 8; ++i) {
                const int s = (g + 1) * 8 + i;
                buf[nb][2*i+0] = *(const float4*)(xp + 16 * s);
                buf[nb][2*i+1] = *(const float4*)(xp + 16 * s + 4);
            }
        }
        #pragma unroll
        for (int i = 0; i < 8; ++i) {
            const int s = g * 8 + i;
            const float4 u0 = buf[cb][2*i+0];
            const float4 u1 = buf[cb][2*i+1];

            x2 += u0.x*u0.x + u0.y*u0.y + u0.z*u0.z + u0.w*u0.w
                + u1.x*u1.x + u1.y*u1.y + u1.z*u1.z + u1.w*u1.w;

            short8 b;
            b[0] = (short)f2bf(u0.x); b[1] = (short)f2bf(u0.y);
            b[2] = (short)f2bf(u0.z); b[3] = (short)f2bf(u0.w);
            b[4] = (short)f2bf(u1.x); b[5] = (short)f2bf(u1.y);
            b[6] = (short)f2bf(u1.z); b[7] = (short)f2bf(u1.w);

            short8 a0 = *(const short8*)&alds[((size_t)(s * 2 + 0) * 64 + lane) * 8];
            short8 a1 = *(const short8*)&alds[((size_t)(s * 2 + 1) * 64 + lane) * 8];

            acc0 = __builtin_amdgcn_mfma_f32_32x32x16_bf16(a0, b, acc0, 0, 0, 0);
            acc1 = __builtin_amdgcn_mfma_f32_32x32x16_bf16(a1, b, acc1, 0, 0, 0);
        }
    }
    x2 += __shfl_xor(x2, 32);   // combine the two k-halves of point n

    // dist in place of acc; C/D: col = lane&31 = point, row = (r&3)+8*(r>>2)+4*h
    float minv = 1e30f;
    #pragma unroll
    for (int r = 0; r < 16; ++r) {
        const int rr = (r & 3) + 8 * (r >> 2) + 4 * h;
        const float d0 = x2 + c2s[rr]      - 2.0f * acc0[r];
        const float d1 = x2 + c2s[rr + 32] - 2.0f * acc1[r];
        acc0[r] = d0; acc1[r] = d1;
        minv = fminf(minv, fminf(d0, d1));
    }
    minv = fminf(minv, __shfl_xor(minv, 32));

    float esum = 0.0f, wsum = 0.0f;
    #pragma unroll
    for (int r = 0; r < 16; ++r) {
        const float e0 = __expf(-alpha * (acc0[r] - minv));
        const float e1 = __expf(-alpha * (acc1[r] - minv));
        esum += e0 + e1;
        wsum += acc0[r] * e0 + acc1[r] * e1;
    }
    esum += __shfl_xor(esum, 32);
    wsum += __shfl_xor(wsum, 32);

    float pv = wsum / esum;                 // per-point value, 2 copies/point
    #pragma unroll
    for (int m = 1; m < 64; m <<= 1) pv += __shfl_xor(pv, m);   // 2 * sum(32 pts)

    if (lane == 0) bsum[w] = pv;
    __syncthreads();
    if (tid == 0) {
        const float T = bsum[0] + bsum[1] + bsum[2] + bsum[3];
        atomicAdd(out, T * (LAMBD / (2.0f * (float)N_POINTS)));
    }
}

extern "C" void kernel_launch(void* const* d_in, const int* in_sizes, int n_in,
                              void* d_out, int out_size, void* d_ws, size_t ws_size,
                              hipStream_t stream) {
    const float* x      = (const float*)d_in[0];
    const float* cent   = (const float*)d_in[1];
    const int*   alphap = (const int*)d_in[2];
    float* out = (float*)d_out;

    float*          c2_ws = (float*)d_ws;                          // 256 B
    unsigned short* afrag = (unsigned short*)((char*)d_ws + 256);  // 64 KiB

    hipLaunchKernelGGL(prep_kernel, dim3(N_CLUSTERS), dim3(64), 0, stream,
                       cent, c2_ws, afrag, out);
    hipLaunchKernelGGL(main_kernel, dim3(N_POINTS / PTS_PER_BLK), dim3(256), 0, stream,
                       x, alphap, c2_ws, afrag, out);
}